// Round 1
// baseline (5670.155 us; speedup 1.0000x reference)
//
#include <hip/hip_runtime.h>
#include <math.h>

#define SEQL 64
#define BATCHN 64
#define HID 1024
#define EMBD 1024
#define VOCAB 10000
#define G3 3072
#define NPAD 10112   // 79*128
#define AROWS 4096   // SEQL*BATCHN

typedef float f4v __attribute__((ext_vector_type(4)));
typedef unsigned short us4 __attribute__((ext_vector_type(4)));
typedef unsigned short us8 __attribute__((ext_vector_type(8)));
typedef __bf16 bf8v __attribute__((ext_vector_type(8)));

__device__ __forceinline__ unsigned short f2bf(float f) {
    unsigned u = __float_as_uint(f);
    u += 0x7fffu + ((u >> 16) & 1u);
    return (unsigned short)(u >> 16);
}
__device__ __forceinline__ float bf2f(unsigned short h) {
    return __uint_as_float(((unsigned)h) << 16);
}
__device__ __forceinline__ void split2(float f, unsigned short &hi, unsigned short &lo) {
    hi = f2bf(f);
    lo = f2bf(f - bf2f(hi));
}
__device__ __forceinline__ f4v mfma16(us8 a, us8 b, f4v c) {
    return __builtin_amdgcn_mfma_f32_16x16x32_bf16(
        __builtin_bit_cast(bf8v, a), __builtin_bit_cast(bf8v, b), c, 0, 0, 0);
}
__device__ __forceinline__ float sigmoidf_(float x) { return 1.f / (1.f + expf(-x)); }

// ---------------- prep: transpose + hi/lo split of the 4 recurrent weights ----------
// in:  W[1024][3072] fp32   out: WT[3072][1024] bf16-hi and bf16-lo, 4 matrices concat
__global__ void transpose_split_kernel(const float* __restrict__ W0, const float* __restrict__ U0,
                                       const float* __restrict__ W1, const float* __restrict__ U1,
                                       unsigned short* __restrict__ outHi, unsigned short* __restrict__ outLo)
{
    __shared__ float tile[32][33];
    int mat = blockIdx.z;
    const float* src = (mat == 0) ? W0 : (mat == 1) ? U0 : (mat == 2) ? W1 : U1;
    unsigned short* dhi = outHi + (size_t)mat * G3 * HID;
    unsigned short* dlo = outLo + (size_t)mat * G3 * HID;
    int n0 = blockIdx.x * 32, k0 = blockIdx.y * 32;
    int tx = threadIdx.x & 31, ty = threadIdx.x >> 5;  // 256 thr: ty 0..7
#pragma unroll
    for (int s = 0; s < 4; s++)
        tile[ty + s * 8][tx] = src[(size_t)(k0 + ty + s * 8) * G3 + n0 + tx];
    __syncthreads();
#pragma unroll
    for (int s = 0; s < 4; s++) {
        int nl = ty + s * 8;
        float v = tile[tx][nl];  // = src[k0+tx][n0+nl]
        unsigned short hi, lo; split2(v, hi, lo);
        size_t o = (size_t)(n0 + nl) * HID + k0 + tx;
        dhi[o] = hi; dlo[o] = lo;
    }
}

// ---------------- prep: pad fcW to NPAD rows + hi/lo split ----------
__global__ void fc_pad_split_kernel(const float* __restrict__ fcW,
                                    unsigned short* __restrict__ hi, unsigned short* __restrict__ lo)
{
    size_t i = ((size_t)blockIdx.x * 256 + threadIdx.x) * 4;
    size_t row = i >> 10;
    f4v v = {0.f, 0.f, 0.f, 0.f};
    if (row < VOCAB) v = *(const f4v*)(fcW + i);
    us4 h, l;
#pragma unroll
    for (int j = 0; j < 4; j++) { unsigned short a, b; split2(v[j], a, b); h[j] = a; l[j] = b; }
    *(us4*)(hi + i) = h;
    *(us4*)(lo + i) = l;
}

// ---------------- prep: fcb pad + initial hidden split ----------
__global__ void small_prep_kernel(const float* __restrict__ fcb, const float* __restrict__ hidden,
                                  float* __restrict__ fcb_pad,
                                  unsigned short* __restrict__ h0ih, unsigned short* __restrict__ h0il,
                                  unsigned short* __restrict__ h1ih, unsigned short* __restrict__ h1il)
{
    int idx = blockIdx.x * 256 + threadIdx.x;
    if (idx < NPAD) fcb_pad[idx] = (idx < VOCAB) ? fcb[idx] : 0.f;
    if (idx < BATCHN * HID) {
        unsigned short a, b;
        split2(hidden[idx], a, b);                 h0ih[idx] = a; h0il[idx] = b;
        split2(hidden[BATCHN * HID + idx], a, b);  h1ih[idx] = a; h1il[idx] = b;
    }
}

// ---------------- GX0 = gather(emb,tok) @ W0  (raw, bias added later) ----------
// 128x128 tile, BK=32, 4 waves (2x2), split-bf16 (3 MFMA / product)
__global__ __launch_bounds__(256)
void gx0_gemm_kernel(const int* __restrict__ tok, const float* __restrict__ emb,
                     const unsigned short* __restrict__ Bhi, const unsigned short* __restrict__ Blo,
                     float* __restrict__ C)
{
    __shared__ unsigned short Ah[128][40], Al[128][40], Bh[128][40], Bl[128][40];
    const int col0 = blockIdx.x * 128;
    const int row0 = blockIdx.y * 128;
    const int tid = threadIdx.x;
    const int lane = tid & 63, wave = tid >> 6;
    const int wm = wave >> 1, wn = wave & 1;
    const int srow = tid >> 1;
    const int shalf = (tid & 1) * 16;

    const float* asrc = emb + (size_t)tok[row0 + srow] * EMBD + shalf;
    const unsigned short* bh_src = Bhi + (size_t)(col0 + srow) * HID + shalf;
    const unsigned short* bl_src = Blo + (size_t)(col0 + srow) * HID + shalf;

    f4v acc[4][4] = {};
    f4v a[4];
    us8 bh2[2], bl2[2];
#pragma unroll
    for (int q = 0; q < 4; q++) a[q] = *(const f4v*)(asrc + q * 4);
    bh2[0] = *(const us8*)(bh_src);     bh2[1] = *(const us8*)(bh_src + 8);
    bl2[0] = *(const us8*)(bl_src);     bl2[1] = *(const us8*)(bl_src + 8);

    const int fr = lane & 15, fk = (lane >> 4) * 8;

    for (int k0 = 0; k0 < EMBD; k0 += 32) {
        __syncthreads();
        us8 ahv[2], alv[2];
#pragma unroll
        for (int q = 0; q < 4; q++)
#pragma unroll
            for (int j = 0; j < 4; j++) {
                unsigned short h, l;
                split2(a[q][j], h, l);
                ahv[q >> 1][(q & 1) * 4 + j] = h;
                alv[q >> 1][(q & 1) * 4 + j] = l;
            }
        *(us8*)(&Ah[srow][shalf]) = ahv[0];     *(us8*)(&Ah[srow][shalf + 8]) = ahv[1];
        *(us8*)(&Al[srow][shalf]) = alv[0];     *(us8*)(&Al[srow][shalf + 8]) = alv[1];
        *(us8*)(&Bh[srow][shalf]) = bh2[0];     *(us8*)(&Bh[srow][shalf + 8]) = bh2[1];
        *(us8*)(&Bl[srow][shalf]) = bl2[0];     *(us8*)(&Bl[srow][shalf + 8]) = bl2[1];
        __syncthreads();
        if (k0 + 32 < EMBD) {  // prefetch next tile into regs, overlaps MFMAs below
#pragma unroll
            for (int q = 0; q < 4; q++) a[q] = *(const f4v*)(asrc + k0 + 32 + q * 4);
            bh2[0] = *(const us8*)(bh_src + k0 + 32);  bh2[1] = *(const us8*)(bh_src + k0 + 40);
            bl2[0] = *(const us8*)(bl_src + k0 + 32);  bl2[1] = *(const us8*)(bl_src + k0 + 40);
        }
        us8 afh[4], afl[4];
#pragma unroll
        for (int m = 0; m < 4; m++) {
            afh[m] = *(const us8*)(&Ah[wm * 64 + m * 16 + fr][fk]);
            afl[m] = *(const us8*)(&Al[wm * 64 + m * 16 + fr][fk]);
        }
#pragma unroll
        for (int n = 0; n < 4; n++) {
            us8 bfh = *(const us8*)(&Bh[wn * 64 + n * 16 + fr][fk]);
            us8 bfl = *(const us8*)(&Bl[wn * 64 + n * 16 + fr][fk]);
#pragma unroll
            for (int m = 0; m < 4; m++) {
                acc[m][n] = mfma16(afh[m], bfh, acc[m][n]);
                acc[m][n] = mfma16(afh[m], bfl, acc[m][n]);
                acc[m][n] = mfma16(afl[m], bfh, acc[m][n]);
            }
        }
    }
    const int fq = lane >> 4;
#pragma unroll
    for (int m = 0; m < 4; m++)
#pragma unroll
        for (int n = 0; n < 4; n++)
#pragma unroll
            for (int i = 0; i < 4; i++) {
                int r = row0 + wm * 64 + m * 16 + fq * 4 + i;
                int c = col0 + wn * 64 + n * 16 + fr;
                C[(size_t)r * G3 + c] = acc[m][n][i];
            }
}

// ---------------- logits = H1 @ fcW^T + fcb ----------
__global__ __launch_bounds__(256)
void logits_gemm_kernel(const unsigned short* __restrict__ Ahi_g, const unsigned short* __restrict__ Alo_g,
                        const unsigned short* __restrict__ Bhi, const unsigned short* __restrict__ Blo,
                        const float* __restrict__ bias, float* __restrict__ C)
{
    __shared__ unsigned short Ah[128][40], Al[128][40], Bh[128][40], Bl[128][40];
    const int col0 = blockIdx.x * 128;
    const int row0 = blockIdx.y * 128;
    const int tid = threadIdx.x;
    const int lane = tid & 63, wave = tid >> 6;
    const int wm = wave >> 1, wn = wave & 1;
    const int srow = tid >> 1;
    const int shalf = (tid & 1) * 16;

    const unsigned short* ah_src = Ahi_g + (size_t)(row0 + srow) * HID + shalf;
    const unsigned short* al_src = Alo_g + (size_t)(row0 + srow) * HID + shalf;
    const unsigned short* bh_src = Bhi + (size_t)(col0 + srow) * HID + shalf;
    const unsigned short* bl_src = Blo + (size_t)(col0 + srow) * HID + shalf;

    f4v acc[4][4] = {};
    us8 ah2[2], al2[2], bh2[2], bl2[2];
    ah2[0] = *(const us8*)(ah_src);  ah2[1] = *(const us8*)(ah_src + 8);
    al2[0] = *(const us8*)(al_src);  al2[1] = *(const us8*)(al_src + 8);
    bh2[0] = *(const us8*)(bh_src);  bh2[1] = *(const us8*)(bh_src + 8);
    bl2[0] = *(const us8*)(bl_src);  bl2[1] = *(const us8*)(bl_src + 8);

    const int fr = lane & 15, fk = (lane >> 4) * 8;

    for (int k0 = 0; k0 < HID; k0 += 32) {
        __syncthreads();
        *(us8*)(&Ah[srow][shalf]) = ah2[0];  *(us8*)(&Ah[srow][shalf + 8]) = ah2[1];
        *(us8*)(&Al[srow][shalf]) = al2[0];  *(us8*)(&Al[srow][shalf + 8]) = al2[1];
        *(us8*)(&Bh[srow][shalf]) = bh2[0];  *(us8*)(&Bh[srow][shalf + 8]) = bh2[1];
        *(us8*)(&Bl[srow][shalf]) = bl2[0];  *(us8*)(&Bl[srow][shalf + 8]) = bl2[1];
        __syncthreads();
        if (k0 + 32 < HID) {
            ah2[0] = *(const us8*)(ah_src + k0 + 32);  ah2[1] = *(const us8*)(ah_src + k0 + 40);
            al2[0] = *(const us8*)(al_src + k0 + 32);  al2[1] = *(const us8*)(al_src + k0 + 40);
            bh2[0] = *(const us8*)(bh_src + k0 + 32);  bh2[1] = *(const us8*)(bh_src + k0 + 40);
            bl2[0] = *(const us8*)(bl_src + k0 + 32);  bl2[1] = *(const us8*)(bl_src + k0 + 40);
        }
        us8 afh[4], afl[4];
#pragma unroll
        for (int m = 0; m < 4; m++) {
            afh[m] = *(const us8*)(&Ah[wm * 64 + m * 16 + fr][fk]);
            afl[m] = *(const us8*)(&Al[wm * 64 + m * 16 + fr][fk]);
        }
#pragma unroll
        for (int n = 0; n < 4; n++) {
            us8 bfh = *(const us8*)(&Bh[wn * 64 + n * 16 + fr][fk]);
            us8 bfl = *(const us8*)(&Bl[wn * 64 + n * 16 + fr][fk]);
#pragma unroll
            for (int m = 0; m < 4; m++) {
                acc[m][n] = mfma16(afh[m], bfh, acc[m][n]);
                acc[m][n] = mfma16(afh[m], bfl, acc[m][n]);
                acc[m][n] = mfma16(afl[m], bfh, acc[m][n]);
            }
        }
    }
    const int fq = lane >> 4;
#pragma unroll
    for (int m = 0; m < 4; m++)
#pragma unroll
        for (int n = 0; n < 4; n++)
#pragma unroll
            for (int i = 0; i < 4; i++) {
                int r = row0 + wm * 64 + m * 16 + fq * 4 + i;
                int c = col0 + wn * 64 + n * 16 + fr;
                float v = acc[m][n][i] + bias[c];
                if (c < VOCAB) C[(size_t)r * VOCAB + c] = v;
            }
}

// ---------------- fused recurrent step ----------
// Computes (if DO_L1) h1_t = GRU1(x=h0_t, h=h1_{t-1})  and (if DO_L0) h0_{t+1} = GRU0(gx0[t+1], h0_t).
// Grid 64 blocks (16 output cols each), 512 threads = 8 waves: wave&3 -> 16 batch rows,
// wave>>2 -> K half (in-block split-K x2, LDS reduce). No LDS tiles: direct 16B frag loads.
template <bool DO_L0, bool DO_L1>
__global__ __launch_bounds__(512)
void step_kernel(const unsigned short* __restrict__ h0hi, const unsigned short* __restrict__ h0lo,
                 const unsigned short* __restrict__ h1hi, const unsigned short* __restrict__ h1lo,
                 const unsigned short* __restrict__ U0Thi, const unsigned short* __restrict__ U0Tlo,
                 const unsigned short* __restrict__ W1Thi, const unsigned short* __restrict__ W1Tlo,
                 const unsigned short* __restrict__ U1Thi, const unsigned short* __restrict__ U1Tlo,
                 const float* __restrict__ gx0next,
                 const float* __restrict__ bw0, const float* __restrict__ bu0,
                 const float* __restrict__ bw1, const float* __restrict__ bu1,
                 const float* __restrict__ h0prev_f, const float* __restrict__ h1prev_f,
                 float* __restrict__ h0out_f, unsigned short* __restrict__ h0out_hi, unsigned short* __restrict__ h0out_lo,
                 float* __restrict__ h1out_f, unsigned short* __restrict__ h1out_hi, unsigned short* __restrict__ h1out_lo)
{
    __shared__ float red[4][9][4][64];
    const int tid = threadIdx.x, lane = tid & 63, wave = tid >> 6;
    const int wrow = wave & 3, ksel = wave >> 2;
    const int j0 = blockIdx.x * 16;
    const int fr = lane & 15, fkb = (lane >> 4) * 8;

    f4v acc[9] = {};
    const size_t aoff = (size_t)(wrow * 16 + fr) * HID;

    for (int ks = ksel * 16; ks < ksel * 16 + 16; ks++) {
        const int kk = ks * 32 + fkb;
        us8 a0h, a0l, a1h, a1l;
        a0h = *(const us8*)(h0hi + aoff + kk);
        a0l = *(const us8*)(h0lo + aoff + kk);
        if (DO_L1) {
            a1h = *(const us8*)(h1hi + aoff + kk);
            a1l = *(const us8*)(h1lo + aoff + kk);
        }
#pragma unroll
        for (int g = 0; g < 3; g++) {
            const size_t boff = (size_t)(g * HID + j0 + fr) * HID + kk;
            if (DO_L0) {
                us8 bh = *(const us8*)(U0Thi + boff), bl = *(const us8*)(U0Tlo + boff);
                acc[g] = mfma16(a0h, bh, acc[g]);
                acc[g] = mfma16(a0h, bl, acc[g]);
                acc[g] = mfma16(a0l, bh, acc[g]);
            }
            if (DO_L1) {
                us8 bh = *(const us8*)(W1Thi + boff), bl = *(const us8*)(W1Tlo + boff);
                acc[3 + g] = mfma16(a0h, bh, acc[3 + g]);
                acc[3 + g] = mfma16(a0h, bl, acc[3 + g]);
                acc[3 + g] = mfma16(a0l, bh, acc[3 + g]);
                us8 ch = *(const us8*)(U1Thi + boff), cl = *(const us8*)(U1Tlo + boff);
                acc[6 + g] = mfma16(a1h, ch, acc[6 + g]);
                acc[6 + g] = mfma16(a1h, cl, acc[6 + g]);
                acc[6 + g] = mfma16(a1l, ch, acc[6 + g]);
            }
        }
    }
    if (ksel == 1) {
#pragma unroll
        for (int t = 0; t < 9; t++)
#pragma unroll
            for (int i = 0; i < 4; i++) red[wrow][t][i][lane] = acc[t][i];
    }
    __syncthreads();
    if (ksel == 0) {
#pragma unroll
        for (int t = 0; t < 9; t++)
#pragma unroll
            for (int i = 0; i < 4; i++) acc[t][i] += red[wrow][t][i][lane];
        const int fq = lane >> 4;
        const int j = j0 + fr;
#pragma unroll
        for (int i = 0; i < 4; i++) {
            const int b = wrow * 16 + fq * 4 + i;
            if (DO_L0) {
                float gxr = gx0next[(size_t)b * G3 + j]            + bw0[j];
                float gxz = gx0next[(size_t)b * G3 + HID + j]      + bw0[HID + j];
                float gxn = gx0next[(size_t)b * G3 + 2 * HID + j]  + bw0[2 * HID + j];
                float ghr = acc[0][i] + bu0[j];
                float ghz = acc[1][i] + bu0[HID + j];
                float ghn = acc[2][i] + bu0[2 * HID + j];
                float r = sigmoidf_(gxr + ghr);
                float z = sigmoidf_(gxz + ghz);
                float ht = tanhf(gxn + r * ghn);
                float hp = h0prev_f[(size_t)b * HID + j];
                float hn = (1.f - z) * hp + z * ht;
                h0out_f[(size_t)b * HID + j] = hn;
                unsigned short hh, hl; split2(hn, hh, hl);
                h0out_hi[(size_t)b * HID + j] = hh;
                h0out_lo[(size_t)b * HID + j] = hl;
            }
            if (DO_L1) {
                float gxr = acc[3][i] + bw1[j];
                float gxz = acc[4][i] + bw1[HID + j];
                float gxn = acc[5][i] + bw1[2 * HID + j];
                float ghr = acc[6][i] + bu1[j];
                float ghz = acc[7][i] + bu1[HID + j];
                float ghn = acc[8][i] + bu1[2 * HID + j];
                float r = sigmoidf_(gxr + ghr);
                float z = sigmoidf_(gxz + ghz);
                float ht = tanhf(gxn + r * ghn);
                float hp = h1prev_f[(size_t)b * HID + j];
                float hn = (1.f - z) * hp + z * ht;
                h1out_f[(size_t)b * HID + j] = hn;
                unsigned short hh, hl; split2(hn, hh, hl);
                h1out_hi[(size_t)b * HID + j] = hh;
                h1out_lo[(size_t)b * HID + j] = hl;
            }
        }
    }
}

__global__ void hidden_out_kernel(const float* __restrict__ h0, const float* __restrict__ h1,
                                  float* __restrict__ out)
{
    int i = blockIdx.x * 256 + threadIdx.x;
    if (i < BATCHN * HID) {
        out[i] = h0[i];
        out[BATCHN * HID + i] = h1[i];
    }
}

extern "C" void kernel_launch(void* const* d_in, const int* in_sizes, int n_in,
                              void* d_out, int out_size, void* d_ws, size_t ws_size,
                              hipStream_t stream)
{
    (void)in_sizes; (void)n_in; (void)out_size;
    const int*   tok    = (const int*)  d_in[0];
    const float* hidden = (const float*)d_in[1];
    const float* emb    = (const float*)d_in[2];
    const float* W0     = (const float*)d_in[3];
    const float* U0     = (const float*)d_in[4];
    const float* bw0    = (const float*)d_in[5];
    const float* bu0    = (const float*)d_in[6];
    const float* W1     = (const float*)d_in[7];
    const float* U1     = (const float*)d_in[8];
    const float* bw1    = (const float*)d_in[9];
    const float* bu1    = (const float*)d_in[10];
    const float* fcW    = (const float*)d_in[11];
    const float* fcb    = (const float*)d_in[12];
    float* out = (float*)d_out;

    char* wsp = (char*)d_ws;
    size_t used = 0;
    auto alloc = [&](size_t bytes) -> char* {
        char* p = wsp + used;
        used += (bytes + 255) & ~(size_t)255;
        return p;
    };
    unsigned short* WThi  = (unsigned short*)alloc((size_t)4 * G3 * HID * 2);
    unsigned short* WTlo  = (unsigned short*)alloc((size_t)4 * G3 * HID * 2);
    unsigned short* fcWhi = (unsigned short*)alloc((size_t)NPAD * HID * 2);
    unsigned short* fcWlo = (unsigned short*)alloc((size_t)NPAD * HID * 2);
    float*          fcbp  = (float*)alloc((size_t)NPAD * 4);
    float*          GX0   = (float*)alloc((size_t)AROWS * G3 * 4);
    unsigned short* H1hi  = (unsigned short*)alloc((size_t)AROWS * HID * 2);
    unsigned short* H1lo  = (unsigned short*)alloc((size_t)AROWS * HID * 2);
    float* h0f[2]; unsigned short *h0hi[2], *h0lo[2]; float* h1f[2];
    for (int i = 0; i < 2; i++) {
        h0f[i]  = (float*)alloc((size_t)BATCHN * HID * 4);
        h0hi[i] = (unsigned short*)alloc((size_t)BATCHN * HID * 2);
        h0lo[i] = (unsigned short*)alloc((size_t)BATCHN * HID * 2);
        h1f[i]  = (float*)alloc((size_t)BATCHN * HID * 4);
    }
    unsigned short* h0ih = (unsigned short*)alloc((size_t)BATCHN * HID * 2);
    unsigned short* h0il = (unsigned short*)alloc((size_t)BATCHN * HID * 2);
    unsigned short* h1ih = (unsigned short*)alloc((size_t)BATCHN * HID * 2);
    unsigned short* h1il = (unsigned short*)alloc((size_t)BATCHN * HID * 2);
    if (used > ws_size) return;  // ws insufficient (need ~161 MB) -> bail, bench will flag

    const unsigned short* U0Thi = WThi + (size_t)1 * G3 * HID;
    const unsigned short* U0Tlo = WTlo + (size_t)1 * G3 * HID;
    const unsigned short* W1Thi = WThi + (size_t)2 * G3 * HID;
    const unsigned short* W1Tlo = WTlo + (size_t)2 * G3 * HID;
    const unsigned short* U1Thi = WThi + (size_t)3 * G3 * HID;
    const unsigned short* U1Tlo = WTlo + (size_t)3 * G3 * HID;

    transpose_split_kernel<<<dim3(96, 32, 4), 256, 0, stream>>>(W0, U0, W1, U1, WThi, WTlo);
    fc_pad_split_kernel<<<NPAD, 256, 0, stream>>>(fcW, fcWhi, fcWlo);
    small_prep_kernel<<<256, 256, 0, stream>>>(fcb, hidden, fcbp, h0ih, h0il, h1ih, h1il);
    gx0_gemm_kernel<<<dim3(G3 / 128, AROWS / 128), 256, 0, stream>>>(tok, emb, WThi, WTlo, GX0);

    // t = "0 prologue": h0_0 from initial hidden
    step_kernel<true, false><<<64, 512, 0, stream>>>(
        h0ih, h0il, h1ih, h1il,
        U0Thi, U0Tlo, W1Thi, W1Tlo, U1Thi, U1Tlo,
        GX0, bw0, bu0, bw1, bu1,
        hidden, hidden + (size_t)BATCHN * HID,
        h0f[0], h0hi[0], h0lo[0],
        h1f[0], H1hi, H1lo);

    for (int t = 0; t < 63; t++) {
        const unsigned short* a1h = (t == 0) ? h1ih : H1hi + (size_t)(t - 1) * BATCHN * HID;
        const unsigned short* a1l = (t == 0) ? h1il : H1lo + (size_t)(t - 1) * BATCHN * HID;
        const float* h1pf = (t == 0) ? hidden + (size_t)BATCHN * HID : h1f[(t - 1) & 1];
        step_kernel<true, true><<<64, 512, 0, stream>>>(
            h0hi[t & 1], h0lo[t & 1], a1h, a1l,
            U0Thi, U0Tlo, W1Thi, W1Tlo, U1Thi, U1Tlo,
            GX0 + (size_t)(t + 1) * BATCHN * G3, bw0, bu0, bw1, bu1,
            h0f[t & 1], h1pf,
            h0f[(t + 1) & 1], h0hi[(t + 1) & 1], h0lo[(t + 1) & 1],
            h1f[t & 1], H1hi + (size_t)t * BATCHN * HID, H1lo + (size_t)t * BATCHN * HID);
    }
    // t = 63: layer-1 only
    step_kernel<false, true><<<64, 512, 0, stream>>>(
        h0hi[1], h0lo[1],
        H1hi + (size_t)62 * BATCHN * HID, H1lo + (size_t)62 * BATCHN * HID,
        U0Thi, U0Tlo, W1Thi, W1Tlo, U1Thi, U1Tlo,
        GX0, bw0, bu0, bw1, bu1,
        h0f[1], h1f[0],
        h0f[0], h0hi[0], h0lo[0],
        h1f[1], H1hi + (size_t)63 * BATCHN * HID, H1lo + (size_t)63 * BATCHN * HID);

    hidden_out_kernel<<<256, 256, 0, stream>>>(h0f[1], h1f[1], out + (size_t)AROWS * VOCAB);
    logits_gemm_kernel<<<dim3(NPAD / 128, AROWS / 128), 256, 0, stream>>>(
        H1hi, H1lo, fcWhi, fcWlo, fcbp, out);
}

// Round 3
// 1729.801 us; speedup vs baseline: 3.2779x; 3.2779x over previous
//
#include <hip/hip_runtime.h>
#include <math.h>

#define SEQL 64
#define BATCHN 64
#define HID 1024
#define EMBD 1024
#define VOCAB 10000
#define G3 3072
#define NPAD 10112   // 79*128
#define AROWS 4096   // SEQL*BATCHN
#define HSLOT 65536  // BATCHN*HID elements per t-slot

typedef float f4v __attribute__((ext_vector_type(4)));
typedef unsigned short us4 __attribute__((ext_vector_type(4)));
typedef unsigned short us8 __attribute__((ext_vector_type(8)));
typedef __bf16 bf8v __attribute__((ext_vector_type(8)));

__device__ __forceinline__ unsigned short f2bf(float f) {
    unsigned u = __float_as_uint(f);
    u += 0x7fffu + ((u >> 16) & 1u);
    return (unsigned short)(u >> 16);
}
__device__ __forceinline__ float bf2f(unsigned short h) {
    return __uint_as_float(((unsigned)h) << 16);
}
__device__ __forceinline__ void split2(float f, unsigned short &hi, unsigned short &lo) {
    hi = f2bf(f);
    lo = f2bf(f - bf2f(hi));
}
__device__ __forceinline__ f4v mfma16(us8 a, us8 b, f4v c) {
    return __builtin_amdgcn_mfma_f32_16x16x32_bf16(
        __builtin_bit_cast(bf8v, a), __builtin_bit_cast(bf8v, b), c, 0, 0, 0);
}
__device__ __forceinline__ float sigmoidf_(float x) { return 1.f / (1.f + expf(-x)); }

// tiled layout for h within one t-slot: [(b>>4)*32 + (j>>5)][lane=((j>>3)&3)*16+(b&15)][e=j&7]
__device__ __forceinline__ size_t htile_off(int b, int j) {
    return ((size_t)((((b >> 4) * 32 + (j >> 5)) * 64) + ((j >> 3) & 3) * 16 + (b & 15))) * 8 + (j & 7);
}

// ---------------- prep: tile 4 weight matrices into MFMA B-fragment order ----------
// src row-major [1024 K][3072 N] fp32 -> Wt[mat][cc=n/16][ks=k/32][lane][8] bf16 hi/lo
// mats: 0=U0, 1=W1, 2=U1, 3=W0
__global__ __launch_bounds__(256)
void tile_weights_kernel(const float* __restrict__ U0, const float* __restrict__ W1,
                         const float* __restrict__ U1, const float* __restrict__ W0,
                         unsigned short* __restrict__ hi, unsigned short* __restrict__ lo)
{
    __shared__ float tile[32][65];
    const int mat = blockIdx.z;
    const float* src = (mat == 0) ? U0 : (mat == 1) ? W1 : (mat == 2) ? U1 : W0;
    const int n0 = blockIdx.x * 64, k0 = blockIdx.y * 32;
    const int t = threadIdx.x, tx = t & 63, ty = t >> 6;
#pragma unroll
    for (int s = 0; s < 8; s++)
        tile[ty * 8 + s][tx] = src[(size_t)(k0 + ty * 8 + s) * G3 + n0 + tx];
    __syncthreads();
    const int c = t >> 6, lane = t & 63, fr = lane & 15, kg = lane >> 4;
    const int cc = (n0 >> 4) + c;
    const size_t off = (((size_t)(mat * 192 + cc) * 32 + (k0 >> 5)) * 64 + lane) * 8;
    us8 h8, l8;
#pragma unroll
    for (int e = 0; e < 8; e++) {
        unsigned short a, b;
        split2(tile[kg * 8 + e][c * 16 + fr], a, b);
        h8[e] = a; l8[e] = b;
    }
    *(us8*)(hi + off) = h8;
    *(us8*)(lo + off) = l8;
}

// ---------------- prep (late): pad fcW to NPAD rows + hi/lo split ----------
__global__ void fc_pad_split_kernel(const float* __restrict__ fcW,
                                    unsigned short* __restrict__ hi, unsigned short* __restrict__ lo)
{
    size_t i = ((size_t)blockIdx.x * 256 + threadIdx.x) * 4;
    size_t row = i >> 10;
    f4v v = {0.f, 0.f, 0.f, 0.f};
    if (row < VOCAB) v = *(const f4v*)(fcW + i);
    us4 h, l;
#pragma unroll
    for (int j = 0; j < 4; j++) { unsigned short a, b; split2(v[j], a, b); h[j] = a; l[j] = b; }
    *(us4*)(hi + i) = h;
    *(us4*)(lo + i) = l;
}

__global__ void fcb_pad_kernel(const float* __restrict__ fcb, float* __restrict__ fcb_pad)
{
    int idx = blockIdx.x * 256 + threadIdx.x;
    if (idx < NPAD) fcb_pad[idx] = (idx < VOCAB) ? fcb[idx] : 0.f;
}

// ---------------- prep: initial hidden -> tiled hi/lo ----------
__global__ void small_prep_kernel(const float* __restrict__ hidden,
                                  unsigned short* __restrict__ h0th, unsigned short* __restrict__ h0tl,
                                  unsigned short* __restrict__ h1th, unsigned short* __restrict__ h1tl)
{
    int idx = blockIdx.x * 256 + threadIdx.x;
    if (idx < BATCHN * HID) {
        int b = idx >> 10, j = idx & 1023;
        size_t o = htile_off(b, j);
        unsigned short a1, b1;
        split2(hidden[idx], a1, b1);                 h0th[o] = a1; h0tl[o] = b1;
        split2(hidden[BATCHN * HID + idx], a1, b1);  h1th[o] = a1; h1tl[o] = b1;
    }
}

// ---------------- GX0 = gather(emb,tok) @ W0  (raw, bias added later) ----------
__global__ __launch_bounds__(256)
void gx0_gemm_kernel(const int* __restrict__ tok, const float* __restrict__ emb,
                     const unsigned short* __restrict__ Wthi, const unsigned short* __restrict__ Wtlo,
                     float* __restrict__ C)
{
    __shared__ unsigned short Ah[128][40], Al[128][40];
    const int col0 = blockIdx.x * 128;
    const int row0 = blockIdx.y * 128;
    const int tid = threadIdx.x;
    const int lane = tid & 63, wave = tid >> 6;
    const int wm = wave >> 1, wn = wave & 1;
    const int srow = tid >> 1;
    const int shalf = (tid & 1) * 16;

    const float* asrc = emb + (size_t)tok[row0 + srow] * EMBD + shalf;
    const int fr = lane & 15, fk = (lane >> 4) * 8;
    const int cc0 = (col0 >> 4) + wn * 4;

    f4v a[4];
#pragma unroll
    for (int q = 0; q < 4; q++) a[q] = *(const f4v*)(asrc + q * 4);

    f4v acc[4][4] = {};
    for (int k0 = 0; k0 < EMBD; k0 += 32) {
        __syncthreads();
        us8 ahv[2], alv[2];
#pragma unroll
        for (int q = 0; q < 4; q++)
#pragma unroll
            for (int j = 0; j < 4; j++) {
                unsigned short h, l;
                split2(a[q][j], h, l);
                ahv[q >> 1][(q & 1) * 4 + j] = h;
                alv[q >> 1][(q & 1) * 4 + j] = l;
            }
        *(us8*)(&Ah[srow][shalf]) = ahv[0];     *(us8*)(&Ah[srow][shalf + 8]) = ahv[1];
        *(us8*)(&Al[srow][shalf]) = alv[0];     *(us8*)(&Al[srow][shalf + 8]) = alv[1];
        __syncthreads();
        if (k0 + 32 < EMBD) {
#pragma unroll
            for (int q = 0; q < 4; q++) a[q] = *(const f4v*)(asrc + k0 + 32 + q * 4);
        }
        const int ks = k0 >> 5;
        us8 bfh[4], bfl[4];
#pragma unroll
        for (int n = 0; n < 4; n++) {
            const size_t bo = (((size_t)(3 * 192 + cc0 + n) * 32 + ks) * 64 + lane) * 8;
            bfh[n] = *(const us8*)(Wthi + bo);
            bfl[n] = *(const us8*)(Wtlo + bo);
        }
        us8 afh[4], afl[4];
#pragma unroll
        for (int m = 0; m < 4; m++) {
            afh[m] = *(const us8*)(&Ah[wm * 64 + m * 16 + fr][fk]);
            afl[m] = *(const us8*)(&Al[wm * 64 + m * 16 + fr][fk]);
        }
#pragma unroll
        for (int n = 0; n < 4; n++)
#pragma unroll
            for (int m = 0; m < 4; m++) {
                acc[m][n] = mfma16(afh[m], bfh[n], acc[m][n]);
                acc[m][n] = mfma16(afh[m], bfl[n], acc[m][n]);
                acc[m][n] = mfma16(afl[m], bfh[n], acc[m][n]);
            }
    }
    const int fq = lane >> 4;
#pragma unroll
    for (int m = 0; m < 4; m++)
#pragma unroll
        for (int n = 0; n < 4; n++)
#pragma unroll
            for (int i = 0; i < 4; i++) {
                int r = row0 + wm * 64 + m * 16 + fq * 4 + i;
                int c = col0 + wn * 64 + n * 16 + fr;
                C[(size_t)r * G3 + c] = acc[m][n][i];
            }
}

// ---------------- logits = H1 @ fcW^T + fcb ; A read directly from tiled per-t h1 ----------
__global__ __launch_bounds__(256)
void logits_gemm_kernel(const unsigned short* __restrict__ h1t_hi, const unsigned short* __restrict__ h1t_lo,
                        const unsigned short* __restrict__ Bhi, const unsigned short* __restrict__ Blo,
                        const float* __restrict__ bias, float* __restrict__ C)
{
    __shared__ unsigned short Bh[128][40], Bl[128][40];
    const int col0 = blockIdx.x * 128;
    const int row0 = blockIdx.y * 128;
    const int t0 = row0 >> 6;                       // 2 t-slots per 128-row tile
    const int tid = threadIdx.x;
    const int lane = tid & 63, wave = tid >> 6;
    const int wm = wave >> 1, wn = wave & 1;
    const int srow = tid >> 1;
    const int shalf = (tid & 1) * 16;

    const unsigned short* bh_src = Bhi + (size_t)(col0 + srow) * HID + shalf;
    const unsigned short* bl_src = Blo + (size_t)(col0 + srow) * HID + shalf;

    f4v acc[4][4] = {};
    us8 bh2[2], bl2[2];
    bh2[0] = *(const us8*)(bh_src);  bh2[1] = *(const us8*)(bh_src + 8);
    bl2[0] = *(const us8*)(bl_src);  bl2[1] = *(const us8*)(bl_src + 8);

    const int fr = lane & 15, fk = (lane >> 4) * 8;
    const size_t abase = ((size_t)(t0 + wm) * 128) * 512 + (size_t)lane * 8;

    for (int k0 = 0; k0 < HID; k0 += 32) {
        __syncthreads();
        *(us8*)(&Bh[srow][shalf]) = bh2[0];  *(us8*)(&Bh[srow][shalf + 8]) = bh2[1];
        *(us8*)(&Bl[srow][shalf]) = bl2[0];  *(us8*)(&Bl[srow][shalf + 8]) = bl2[1];
        __syncthreads();
        if (k0 + 32 < HID) {
            bh2[0] = *(const us8*)(bh_src + k0 + 32);  bh2[1] = *(const us8*)(bh_src + k0 + 40);
            bl2[0] = *(const us8*)(bl_src + k0 + 32);  bl2[1] = *(const us8*)(bl_src + k0 + 40);
        }
        const int ks = k0 >> 5;
        us8 afh[4], afl[4];
#pragma unroll
        for (int m = 0; m < 4; m++) {
            const size_t ao = abase + (size_t)(m * 32 + ks) * 512;
            afh[m] = *(const us8*)(h1t_hi + ao);
            afl[m] = *(const us8*)(h1t_lo + ao);
        }
#pragma unroll
        for (int n = 0; n < 4; n++) {
            us8 bfh = *(const us8*)(&Bh[wn * 64 + n * 16 + fr][fk]);
            us8 bfl = *(const us8*)(&Bl[wn * 64 + n * 16 + fr][fk]);
#pragma unroll
            for (int m = 0; m < 4; m++) {
                acc[m][n] = mfma16(afh[m], bfh, acc[m][n]);
                acc[m][n] = mfma16(afh[m], bfl, acc[m][n]);
                acc[m][n] = mfma16(afl[m], bfh, acc[m][n]);
            }
        }
    }
    const int fq = lane >> 4;
#pragma unroll
    for (int m = 0; m < 4; m++)
#pragma unroll
        for (int n = 0; n < 4; n++)
#pragma unroll
            for (int i = 0; i < 4; i++) {
                int r = row0 + wm * 64 + m * 16 + fq * 4 + i;
                int c = col0 + wn * 64 + n * 16 + fr;
                float v = acc[m][n][i] + bias[c];
                if (c < VOCAB) C[(size_t)r * VOCAB + c] = v;
            }
}

// ---------------- fused recurrent step (write-once per-t buffers) ----------
// grid dim3(64 jchunks, 4 rowgroups), 512 thr = 8 waves; wave w covers ks=w*4..w*4+3 (K-split x8).
template <bool DO_L0, bool DO_L1>
__global__ __launch_bounds__(512)
void step_kernel(const unsigned short* __restrict__ h0hi, const unsigned short* __restrict__ h0lo,
                 const unsigned short* __restrict__ h1hi, const unsigned short* __restrict__ h1lo,
                 const unsigned short* __restrict__ Wthi, const unsigned short* __restrict__ Wtlo,
                 const float* __restrict__ gx0next,
                 const float* __restrict__ bw0, const float* __restrict__ bu0,
                 const float* __restrict__ bw1, const float* __restrict__ bu1,
                 unsigned short* __restrict__ h0o_hi, unsigned short* __restrict__ h0o_lo,
                 unsigned short* __restrict__ h1o_hi, unsigned short* __restrict__ h1o_lo)
{
    __shared__ float red[4][9][16][17];
    const int tid = threadIdx.x, lane = tid & 63, wave = tid >> 6;
    const int j0 = blockIdx.x * 16, wr = blockIdx.y;
    const int jc = j0 >> 4;
    const int T0 = DO_L0 ? 0 : 3, T1 = DO_L1 ? 9 : 3;

    f4v acc[9] = {};
#pragma unroll 2
    for (int ksl = 0; ksl < 4; ksl++) {
        const int ks = wave * 4 + ksl;
        const size_t aoff = ((size_t)(wr * 32 + ks) * 64 + lane) * 8;
        us8 a0h = *(const us8*)(h0hi + aoff);
        us8 a0l = *(const us8*)(h0lo + aoff);
        us8 a1h = {}, a1l = {};
        if (DO_L1) { a1h = *(const us8*)(h1hi + aoff); a1l = *(const us8*)(h1lo + aoff); }
#pragma unroll
        for (int g = 0; g < 3; g++) {
            const size_t base = (((size_t)(g * 64 + jc) * 32 + ks) * 64 + lane) * 8;
            if (DO_L0) {
                us8 bh = *(const us8*)(Wthi + base);   // mat 0 = U0
                us8 bl = *(const us8*)(Wtlo + base);
                acc[g] = mfma16(a0h, bh, acc[g]);
                acc[g] = mfma16(a0h, bl, acc[g]);
                acc[g] = mfma16(a0l, bh, acc[g]);
            }
            if (DO_L1) {
                const size_t b1 = base + (size_t)192 * 32 * 64 * 8;       // mat 1 = W1
                us8 bh = *(const us8*)(Wthi + b1);
                us8 bl = *(const us8*)(Wtlo + b1);
                acc[3 + g] = mfma16(a0h, bh, acc[3 + g]);
                acc[3 + g] = mfma16(a0h, bl, acc[3 + g]);
                acc[3 + g] = mfma16(a0l, bh, acc[3 + g]);
                const size_t b2 = base + (size_t)2 * 192 * 32 * 64 * 8;   // mat 2 = U1
                us8 ch = *(const us8*)(Wthi + b2);
                us8 cl = *(const us8*)(Wtlo + b2);
                acc[6 + g] = mfma16(a1h, ch, acc[6 + g]);
                acc[6 + g] = mfma16(a1h, cl, acc[6 + g]);
                acc[6 + g] = mfma16(a1l, ch, acc[6 + g]);
            }
        }
    }
    const int rrow = (lane >> 4) * 4, rcol = lane & 15;
    if (wave >= 4) {
#pragma unroll
        for (int t2 = 0; t2 < 9; t2++) if (t2 >= T0 && t2 < T1)
#pragma unroll
            for (int i = 0; i < 4; i++) red[wave - 4][t2][rrow + i][rcol] = acc[t2][i];
    }
    __syncthreads();
    if (wave < 4) {
#pragma unroll
        for (int t2 = 0; t2 < 9; t2++) if (t2 >= T0 && t2 < T1)
#pragma unroll
            for (int i = 0; i < 4; i++)
                red[wave][t2][rrow + i][rcol] += acc[t2][i];
    }
    __syncthreads();
    if (tid < 256) {
        const int bl_ = tid >> 4, jl = tid & 15;
        const int b = wr * 16 + bl_, j = j0 + jl;
        float G[9];
#pragma unroll
        for (int t2 = 0; t2 < 9; t2++) if (t2 >= T0 && t2 < T1)
            G[t2] = (red[0][t2][bl_][jl] + red[1][t2][bl_][jl])
                  + (red[2][t2][bl_][jl] + red[3][t2][bl_][jl]);
        const size_t po = htile_off(b, j);
        if (DO_L0) {
            float sr = gx0next[(size_t)b * G3 + j]            + bw0[j]           + G[0] + bu0[j];
            float sz = gx0next[(size_t)b * G3 + HID + j]      + bw0[HID + j]     + G[1] + bu0[HID + j];
            float gxn = gx0next[(size_t)b * G3 + 2 * HID + j] + bw0[2 * HID + j];
            float ghn = G[2] + bu0[2 * HID + j];
            float r = sigmoidf_(sr);
            float z = sigmoidf_(sz);
            float ht = tanhf(gxn + r * ghn);
            float hp = bf2f(h0hi[po]) + bf2f(h0lo[po]);
            float hn = (1.f - z) * hp + z * ht;
            unsigned short hh, hl2; split2(hn, hh, hl2);
            h0o_hi[po] = hh; h0o_lo[po] = hl2;
        }
        if (DO_L1) {
            float sr = G[3] + bw1[j]           + G[6] + bu1[j];
            float sz = G[4] + bw1[HID + j]     + G[7] + bu1[HID + j];
            float gxn = G[5] + bw1[2 * HID + j];
            float ghn = G[8] + bu1[2 * HID + j];
            float r = sigmoidf_(sr);
            float z = sigmoidf_(sz);
            float ht = tanhf(gxn + r * ghn);
            float hp = bf2f(h1hi[po]) + bf2f(h1lo[po]);
            float hn = (1.f - z) * hp + z * ht;
            unsigned short hh, hl2; split2(hn, hh, hl2);
            h1o_hi[po] = hh; h1o_lo[po] = hl2;
        }
    }
}

// ---------------- final hidden output (reconstruct f32 = hi + lo) ----------
__global__ void hidden_out_kernel(const unsigned short* __restrict__ h0hi, const unsigned short* __restrict__ h0lo,
                                  const unsigned short* __restrict__ h1hi, const unsigned short* __restrict__ h1lo,
                                  float* __restrict__ out)
{
    int i = blockIdx.x * 256 + threadIdx.x;
    if (i < BATCHN * HID) {
        int b = i >> 10, j = i & 1023;
        size_t o = htile_off(b, j);
        out[i] = bf2f(h0hi[o]) + bf2f(h0lo[o]);
        out[BATCHN * HID + i] = bf2f(h1hi[o]) + bf2f(h1lo[o]);
    }
}

extern "C" void kernel_launch(void* const* d_in, const int* in_sizes, int n_in,
                              void* d_out, int out_size, void* d_ws, size_t ws_size,
                              hipStream_t stream)
{
    (void)in_sizes; (void)n_in; (void)out_size;
    const int*   tok    = (const int*)  d_in[0];
    const float* hidden = (const float*)d_in[1];
    const float* emb    = (const float*)d_in[2];
    const float* W0     = (const float*)d_in[3];
    const float* U0     = (const float*)d_in[4];
    const float* bw0    = (const float*)d_in[5];
    const float* bu0    = (const float*)d_in[6];
    const float* W1     = (const float*)d_in[7];
    const float* U1     = (const float*)d_in[8];
    const float* bw1    = (const float*)d_in[9];
    const float* bu1    = (const float*)d_in[10];
    const float* fcW    = (const float*)d_in[11];
    const float* fcb    = (const float*)d_in[12];
    float* out = (float*)d_out;

    char* wsp = (char*)d_ws;
    size_t used = 0;
    auto alloc = [&](size_t bytes) -> char* {
        char* p = wsp + used;
        used += (bytes + 255) & ~(size_t)255;
        return p;
    };
    unsigned short* Wt_hi = (unsigned short*)alloc((size_t)4 * G3 * HID * 2);   // 25.2 MB
    unsigned short* Wt_lo = (unsigned short*)alloc((size_t)4 * G3 * HID * 2);   // 25.2 MB
    float*          GX0   = (float*)alloc((size_t)AROWS * G3 * 4);              // 50.3 MB
    unsigned short* H0Thi = (unsigned short*)alloc((size_t)SEQL * HSLOT * 2);   // 8.4 MB (slot t = h0_t)
    unsigned short* H0Tlo = (unsigned short*)alloc((size_t)SEQL * HSLOT * 2);
    unsigned short* H1Thi = (unsigned short*)alloc((size_t)SEQL * HSLOT * 2);   // slot t = h1_t
    unsigned short* H1Tlo = (unsigned short*)alloc((size_t)SEQL * HSLOT * 2);
    unsigned short* h0ith = (unsigned short*)alloc((size_t)HSLOT * 2);
    unsigned short* h0itl = (unsigned short*)alloc((size_t)HSLOT * 2);
    unsigned short* h1ith = (unsigned short*)alloc((size_t)HSLOT * 2);
    unsigned short* h1itl = (unsigned short*)alloc((size_t)HSLOT * 2);
    if (used > ws_size) return;  // ~135 MB needed

    // fcW split + fcb pad alias into the Wt region (Wt is dead after the last step;
    // fc prep kernels run after the final step, before logits).
    unsigned short* fcWhi = Wt_hi;                               // 20.71 MB < 25.17 MB
    unsigned short* fcWlo = Wt_lo;
    float*          fcbp  = (float*)((char*)Wt_hi + (size_t)NPAD * HID * 2);  // 40 KB tail, 256B-aligned

    tile_weights_kernel<<<dim3(48, 32, 4), 256, 0, stream>>>(U0, W1, U1, W0, Wt_hi, Wt_lo);
    small_prep_kernel<<<256, 256, 0, stream>>>(hidden, h0ith, h0itl, h1ith, h1itl);
    gx0_gemm_kernel<<<dim3(G3 / 128, AROWS / 128), 256, 0, stream>>>(tok, emb, Wt_hi, Wt_lo, GX0);

    // prologue: h0_0 = GRU0(gx0[0], h_init0)   (h1 params unused reads/writes)
    step_kernel<true, false><<<dim3(64, 4), 512, 0, stream>>>(
        h0ith, h0itl, h1ith, h1itl, Wt_hi, Wt_lo,
        GX0, bw0, bu0, bw1, bu1,
        H0Thi, H0Tlo,                                  // h0_0 -> slot 0
        H1Thi + (size_t)63 * HSLOT, H1Tlo + (size_t)63 * HSLOT);  // dummy (never written)

    for (int t = 0; t < 63; t++) {
        const unsigned short* a1h = (t == 0) ? h1ith : H1Thi + (size_t)(t - 1) * HSLOT;
        const unsigned short* a1l = (t == 0) ? h1itl : H1Tlo + (size_t)(t - 1) * HSLOT;
        step_kernel<true, true><<<dim3(64, 4), 512, 0, stream>>>(
            H0Thi + (size_t)t * HSLOT, H0Tlo + (size_t)t * HSLOT,   // h0_t
            a1h, a1l,                                               // h1_{t-1}
            Wt_hi, Wt_lo,
            GX0 + (size_t)(t + 1) * BATCHN * G3, bw0, bu0, bw1, bu1,
            H0Thi + (size_t)(t + 1) * HSLOT, H0Tlo + (size_t)(t + 1) * HSLOT,  // h0_{t+1}
            H1Thi + (size_t)t * HSLOT, H1Tlo + (size_t)t * HSLOT);             // h1_t
    }
    // t = 63: layer-1 only
    step_kernel<false, true><<<dim3(64, 4), 512, 0, stream>>>(
        H0Thi + (size_t)63 * HSLOT, H0Tlo + (size_t)63 * HSLOT,     // h0_63
        H1Thi + (size_t)62 * HSLOT, H1Tlo + (size_t)62 * HSLOT,     // h1_62
        Wt_hi, Wt_lo,
        GX0, bw0, bu0, bw1, bu1,
        h0ith, h0itl,                                               // dummy (never written)
        H1Thi + (size_t)63 * HSLOT, H1Tlo + (size_t)63 * HSLOT);    // h1_63

    hidden_out_kernel<<<256, 256, 0, stream>>>(
        H0Thi + (size_t)63 * HSLOT, H0Tlo + (size_t)63 * HSLOT,
        H1Thi + (size_t)63 * HSLOT, H1Tlo + (size_t)63 * HSLOT,
        out + (size_t)AROWS * VOCAB);

    // fc weight prep (aliases dead Wt space), then logits
    fc_pad_split_kernel<<<NPAD, 256, 0, stream>>>(fcW, fcWhi, fcWlo);
    fcb_pad_kernel<<<(NPAD + 255) / 256, 256, 0, stream>>>(fcb, fcbp);
    logits_gemm_kernel<<<dim3(NPAD / 128, AROWS / 128), 256, 0, stream>>>(
        H1Thi, H1Tlo, fcWhi, fcWlo, fcbp, out);
}